// Round 2
// baseline (667.057 us; speedup 1.0000x reference)
//
#include <hip/hip_runtime.h>
#include <cstdint>
#include <cstddef>

#define D 128
#define CAP 64   // max in-degree; Binomial(800k,1/50k)~Poisson(16), P(deg>64)~1e-19

typedef float f4v __attribute__((ext_vector_type(4)));

static __device__ __forceinline__ float ssp(float x) {
    // softplus(x) - ln2, overflow-safe
    float ax = fabsf(x);
    return fmaxf(x, 0.0f) + log1pf(__expf(-ax)) - 0.6931471805599453f;
}

// K0: fused setup — zero cnt + transpose both weight matrices.
// Blocks 0,1 transpose W1/W2 (write-coalesced); blocks 2.. zero cnt.
__global__ void setup(const float* __restrict__ W1, const float* __restrict__ W2,
                      float* __restrict__ WT1, float* __restrict__ WT2,
                      int* __restrict__ cnt, int N) {
    int b = blockIdx.x;
    if (b < 2) {
        const float* W  = b ? W2 : W1;
        float*       WT = b ? WT2 : WT1;
        for (int idx = threadIdx.x; idx < D * D; idx += 256) {
            // WT[k*D+j] = W[j*D+k]; idx = k*D+j
            WT[idx] = W[((idx & (D - 1)) << 7) | (idx >> 7)];
        }
    } else {
        int i = (b - 2) * 256 + threadIdx.x;
        if (i < N) cnt[i] = 0;
    }
}

// K1: bucket edge ids by destination (count + fill in one pass).
__global__ void build_lists(const int* __restrict__ ei, int E,
                            int* __restrict__ cnt, int* __restrict__ slots) {
    int t = blockIdx.x * blockDim.x + threadIdx.x;
    if (t < E) {
        int dst = __builtin_nontemporal_load(ei + E + t);   // edge_index[1][t]
        int slot = atomicAdd(&cnt[dst], 1);
        if (slot < CAP) slots[(size_t)dst * CAP + slot] = t;
    }
}

// Slot lookup: half-wave holds the node's 64 slot ids as int2 per lane
// (slots[2*l32], slots[2*l32+1]); idx is uniform across the half-wave.
static __device__ __forceinline__ int pickEid(const int2 eid2, int idx) {
    int v = (idx & 1) ? eid2.y : eid2.x;
    return __shfl(v, idx >> 1, 32);
}

// Non-temporal 16B load of single-use streams (don't thrash L2/L3).
static __device__ __forceinline__ f4v ldnt(const float* p) {
    return __builtin_nontemporal_load((const f4v*)p);
}

// K3: fused gather + MLP + residual.
// Block = 256 threads (4 waves = 8 half-waves), 32 node rows/block.
// Phase 1: dynamic (ticketed) node->half-wave assignment, 8 independent
//          512B row loads in flight per half-wave, masked depth-4 tail.
// Phase 2: packed-FMA (v_pk_fma_f32) MLP; H is aliased onto As (all
//          phase-2 row sharing is intra-half-wave and DS ops are in-order
//          per wave, so no barrier is needed between GEMM1 and GEMM2).
__global__ __launch_bounds__(256) void fused_gather_mlp(
    const float* __restrict__ e, const int* __restrict__ cnt,
    const int* __restrict__ slots, const float* __restrict__ vin,
    const float* __restrict__ WT1, const float* __restrict__ b1,
    const float* __restrict__ WT2, const float* __restrict__ b2,
    float* __restrict__ out, int N) {
    __shared__ __align__(16) float As[32][D];
    __shared__ int ticket;
    const int tid  = threadIdx.x;
    const int row0 = blockIdx.x * 32;
    const int l32  = tid & 31;    // float4 index within the 128-float row

    if (tid == 0) ticket = 0;
    __syncthreads();

    // ---- Phase 1: gather-sum edge rows, dynamic node per half-wave ----
    for (;;) {
        int r = 0;
        if (l32 == 0) r = atomicAdd(&ticket, 1);
        r = __shfl(r, 0, 32);
        if (r >= 32) break;
        const int n = row0 + r;
        f4v s0 = 0.f, s1 = 0.f, s2 = 0.f, s3 = 0.f;
        if (n < N) {
            int c = cnt[n];
            if (c > CAP) c = CAP;
            const int2 eid2 = ((const int2*)(slots + (size_t)n * CAP))[l32];
            int j = 0;
            // main: 8 independent 512B row loads in flight per half-wave
            for (; j + 8 <= c; j += 8) {
                int e0 = pickEid(eid2, j + 0);
                int e1 = pickEid(eid2, j + 1);
                int e2 = pickEid(eid2, j + 2);
                int e3 = pickEid(eid2, j + 3);
                int e4 = pickEid(eid2, j + 4);
                int e5 = pickEid(eid2, j + 5);
                int e6 = pickEid(eid2, j + 6);
                int e7 = pickEid(eid2, j + 7);
                f4v x0 = ldnt(e + (size_t)e0 * D + l32 * 4);
                f4v x1 = ldnt(e + (size_t)e1 * D + l32 * 4);
                f4v x2 = ldnt(e + (size_t)e2 * D + l32 * 4);
                f4v x3 = ldnt(e + (size_t)e3 * D + l32 * 4);
                f4v x4 = ldnt(e + (size_t)e4 * D + l32 * 4);
                f4v x5 = ldnt(e + (size_t)e5 * D + l32 * 4);
                f4v x6 = ldnt(e + (size_t)e6 * D + l32 * 4);
                f4v x7 = ldnt(e + (size_t)e7 * D + l32 * 4);
                s0 += x0; s1 += x1; s2 += x2; s3 += x3;
                s0 += x4; s1 += x5; s2 += x6; s3 += x7;
            }
            // tail: masked depth-4 (<=2 iterations); masked slots dup edge j
            for (; j < c; j += 4) {
                const int  i1 = (j + 1 < c) ? j + 1 : j;
                const int  i2 = (j + 2 < c) ? j + 2 : j;
                const int  i3 = (j + 3 < c) ? j + 3 : j;
                const float w1 = (j + 1 < c) ? 1.f : 0.f;
                const float w2 = (j + 2 < c) ? 1.f : 0.f;
                const float w3 = (j + 3 < c) ? 1.f : 0.f;
                int e0 = pickEid(eid2, j);
                int e1 = pickEid(eid2, i1);
                int e2 = pickEid(eid2, i2);
                int e3 = pickEid(eid2, i3);
                f4v x0 = ldnt(e + (size_t)e0 * D + l32 * 4);
                f4v x1 = ldnt(e + (size_t)e1 * D + l32 * 4);
                f4v x2 = ldnt(e + (size_t)e2 * D + l32 * 4);
                f4v x3 = ldnt(e + (size_t)e3 * D + l32 * 4);
                s0 += x0;
                s1 += x1 * w1;
                s2 += x2 * w2;
                s3 += x3 * w3;
            }
        }
        f4v t4 = (s0 + s1) + (s2 + s3);
        *((f4v*)(&As[r][0]) + l32) = t4;
    }
    __syncthreads();

    // ---- Phase 2: MLP (packed fp32 FMA) ----
    const int jg = (tid & 31) << 2;    // col group: lanes 0..31 contiguous -> coalesced W
    const int rg = (tid >> 5) << 2;    // row group: half-wave uniform -> LDS broadcast

    f4v acc0 = 0.f, acc1 = 0.f, acc2 = 0.f, acc3 = 0.f;
    for (int k = 0; k < D; k += 4) {
        f4v w0 = *(const f4v*)(WT1 + (size_t)(k + 0) * D + jg);
        f4v w1 = *(const f4v*)(WT1 + (size_t)(k + 1) * D + jg);
        f4v w2 = *(const f4v*)(WT1 + (size_t)(k + 2) * D + jg);
        f4v w3 = *(const f4v*)(WT1 + (size_t)(k + 3) * D + jg);
        f4v a0 = *(const f4v*)(&As[rg + 0][k]);
        f4v a1 = *(const f4v*)(&As[rg + 1][k]);
        f4v a2 = *(const f4v*)(&As[rg + 2][k]);
        f4v a3 = *(const f4v*)(&As[rg + 3][k]);
        acc0 += a0.x * w0; acc0 += a0.y * w1; acc0 += a0.z * w2; acc0 += a0.w * w3;
        acc1 += a1.x * w0; acc1 += a1.y * w1; acc1 += a1.z * w2; acc1 += a1.w * w3;
        acc2 += a2.x * w0; acc2 += a2.y * w1; acc2 += a2.z * w2; acc2 += a2.w * w3;
        acc3 += a3.x * w0; acc3 += a3.y * w1; acc3 += a3.z * w2; acc3 += a3.w * w3;
    }
    {
        f4v bb = *(const f4v*)(b1 + jg);
        f4v h0 = acc0 + bb, h1 = acc1 + bb, h2 = acc2 + bb, h3 = acc3 + bb;
        h0.x = ssp(h0.x); h0.y = ssp(h0.y); h0.z = ssp(h0.z); h0.w = ssp(h0.w);
        h1.x = ssp(h1.x); h1.y = ssp(h1.y); h1.z = ssp(h1.z); h1.w = ssp(h1.w);
        h2.x = ssp(h2.x); h2.y = ssp(h2.y); h2.z = ssp(h2.z); h2.w = ssp(h2.w);
        h3.x = ssp(h3.x); h3.y = ssp(h3.y); h3.z = ssp(h3.z); h3.w = ssp(h3.w);
        // H aliased onto As: rows rg..rg+3 are read/written only by this
        // half-wave (lockstep wave, in-order DS) -> no barrier needed.
        *(f4v*)(&As[rg + 0][jg]) = h0;
        *(f4v*)(&As[rg + 1][jg]) = h1;
        *(f4v*)(&As[rg + 2][jg]) = h2;
        *(f4v*)(&As[rg + 3][jg]) = h3;
    }

    acc0 = 0.f; acc1 = 0.f; acc2 = 0.f; acc3 = 0.f;
    for (int k = 0; k < D; k += 4) {
        f4v w0 = *(const f4v*)(WT2 + (size_t)(k + 0) * D + jg);
        f4v w1 = *(const f4v*)(WT2 + (size_t)(k + 1) * D + jg);
        f4v w2 = *(const f4v*)(WT2 + (size_t)(k + 2) * D + jg);
        f4v w3 = *(const f4v*)(WT2 + (size_t)(k + 3) * D + jg);
        f4v a0 = *(const f4v*)(&As[rg + 0][k]);
        f4v a1 = *(const f4v*)(&As[rg + 1][k]);
        f4v a2 = *(const f4v*)(&As[rg + 2][k]);
        f4v a3 = *(const f4v*)(&As[rg + 3][k]);
        acc0 += a0.x * w0; acc0 += a0.y * w1; acc0 += a0.z * w2; acc0 += a0.w * w3;
        acc1 += a1.x * w0; acc1 += a1.y * w1; acc1 += a1.z * w2; acc1 += a1.w * w3;
        acc2 += a2.x * w0; acc2 += a2.y * w1; acc2 += a2.z * w2; acc2 += a2.w * w3;
        acc3 += a3.x * w0; acc3 += a3.y * w1; acc3 += a3.z * w2; acc3 += a3.w * w3;
    }
    {
        f4v bb = *(const f4v*)(b2 + jg);
        const int r0 = row0 + rg;
        if (r0 + 0 < N) {
            f4v vv = ldnt(vin + (size_t)(r0 + 0) * D + jg);
            f4v o = vv + acc0 + bb;
            __builtin_nontemporal_store(o, (f4v*)(out + (size_t)(r0 + 0) * D + jg));
        }
        if (r0 + 1 < N) {
            f4v vv = ldnt(vin + (size_t)(r0 + 1) * D + jg);
            f4v o = vv + acc1 + bb;
            __builtin_nontemporal_store(o, (f4v*)(out + (size_t)(r0 + 1) * D + jg));
        }
        if (r0 + 2 < N) {
            f4v vv = ldnt(vin + (size_t)(r0 + 2) * D + jg);
            f4v o = vv + acc2 + bb;
            __builtin_nontemporal_store(o, (f4v*)(out + (size_t)(r0 + 2) * D + jg));
        }
        if (r0 + 3 < N) {
            f4v vv = ldnt(vin + (size_t)(r0 + 3) * D + jg);
            f4v o = vv + acc3 + bb;
            __builtin_nontemporal_store(o, (f4v*)(out + (size_t)(r0 + 3) * D + jg));
        }
    }
}

extern "C" void kernel_launch(void* const* d_in, const int* in_sizes, int n_in,
                              void* d_out, int out_size, void* d_ws, size_t ws_size,
                              hipStream_t stream) {
    const float* v  = (const float*)d_in[0];
    const float* e  = (const float*)d_in[1];
    const int*   ei = (const int*)d_in[2];      // int32 on device per harness contract
    const float* W1 = (const float*)d_in[3];
    const float* b1 = (const float*)d_in[4];
    const float* W2 = (const float*)d_in[5];
    const float* b2 = (const float*)d_in[6];

    const int N = in_sizes[0] / D;   // 50000
    const int E = in_sizes[1] / D;   // 800000

    // Workspace (~13.2 MB), 256B-aligned chunks.
    char*  ws  = (char*)d_ws;
    size_t off = 0;
    auto alloc = [&](size_t bytes) {
        void* p = ws + off;
        off += (bytes + 255) & ~(size_t)255;
        return p;
    };
    int*   cnt   = (int*)alloc((size_t)N * 4);
    int*   slots = (int*)alloc((size_t)N * CAP * 4);
    float* WT1   = (float*)alloc((size_t)D * D * 4);
    float* WT2   = (float*)alloc((size_t)D * D * 4);
    (void)ws_size; (void)n_in; (void)out_size;

    setup<<<2 + (N + 255) / 256, 256, 0, stream>>>(W1, W2, WT1, WT2, cnt, N);
    build_lists<<<(E + 255) / 256, 256, 0, stream>>>(ei, E, cnt, slots);
    fused_gather_mlp<<<(N + 31) / 32, 256, 0, stream>>>(
        e, cnt, slots, v, WT1, b1, WT2, b2, (float*)d_out, N);
}